// Round 14
// baseline (744.586 us; speedup 1.0000x reference)
//
#include <hip/hip_runtime.h>

// MultiHeadAttention: v(8,1024,512) fp32, pad(8,1,1,1024) int, W1(512,2048), b1(2048),
// W2(8192,512), b2(512) -> out (8,1024,512) fp32 ++ attn (8,16,1024,1024) fp32.
// All matmuls in bf16 MFMA 16x16x32, fp32 accumulate.
// R14: scores reverted to R11 (E_lds + vector stores - R13's scalar reg-direct
//      stores regressed). pv -> BM=256/BN=128, 512 threads: half the barrier
//      cost per MFMA, 3 gloads/thread/step instead of 4.

typedef __attribute__((ext_vector_type(8))) short bf16x8;
typedef __attribute__((ext_vector_type(4))) float f32x4;
typedef __attribute__((ext_vector_type(4))) unsigned short u16x4;

__device__ __forceinline__ unsigned short f2bf(float f) {
  unsigned u = __builtin_bit_cast(unsigned, f);
  u += 0x7FFFu + ((u >> 16) & 1u);   // RTN-even
  return (unsigned short)(u >> 16);
}
__device__ __forceinline__ float bf2f(unsigned short u) {
  return __builtin_bit_cast(float, (unsigned)u << 16);
}

__device__ __forceinline__ void gload_lds16(const unsigned short* g, unsigned short* l) {
  __builtin_amdgcn_global_load_lds(
      (const __attribute__((address_space(1))) unsigned int*)(g),
      (__attribute__((address_space(3))) unsigned int*)(l), 16, 0, 0);
}

// ---------------- preprocessing ----------------

__global__ void cvt_bf16_kernel(const float* __restrict__ in,
                                unsigned short* __restrict__ out, int n4) {
  int i = blockIdx.x * blockDim.x + threadIdx.x;
  if (i >= n4) return;
  f32x4 v = reinterpret_cast<const f32x4*>(in)[i];
  u16x4 o;
#pragma unroll
  for (int j = 0; j < 4; ++j) o[j] = f2bf(v[j]);
  reinterpret_cast<u16x4*>(out)[i] = o;
}

// in fp32 [R][C] -> out bf16 [C][R]
__global__ void transpose_cvt_kernel(const float* __restrict__ in,
                                     unsigned short* __restrict__ out,
                                     int R, int C) {
  __shared__ float tile[32][33];
  int c0 = blockIdx.x * 32, r0 = blockIdx.y * 32;
  int tx = threadIdx.x & 31, ty = threadIdx.x >> 5;
#pragma unroll
  for (int i = ty; i < 32; i += 8)
    tile[i][tx] = in[(size_t)(r0 + i) * C + (c0 + tx)];
  __syncthreads();
#pragma unroll
  for (int i = ty; i < 32; i += 8)
    out[(size_t)(c0 + i) * R + (r0 + tx)] = f2bf(tile[tx][i]);
}

// ---------------- GEMM1: kq = v @ W1 + b1 ----------------
__launch_bounds__(256)
__global__ void gemm1_kernel(const unsigned short* __restrict__ vbf,
                             const unsigned short* __restrict__ w1t,
                             const float* __restrict__ b1,
                             unsigned short* __restrict__ q_ws,
                             unsigned short* __restrict__ k_ws) {
  const int m0 = blockIdx.y * 128, n0 = blockIdx.x * 128;
  const int w = threadIdx.x >> 6, l = threadIdx.x & 63;
  const int wr = w >> 1, wc = w & 1, lr = l & 15, lg = l >> 4;
  f32x4 acc[4][4];
#pragma unroll
  for (int mi = 0; mi < 4; ++mi)
#pragma unroll
    for (int ni = 0; ni < 4; ++ni) acc[mi][ni] = (f32x4){0.f, 0.f, 0.f, 0.f};

  for (int k0 = 0; k0 < 512; k0 += 32) {
    bf16x8 a[4], bb[4];
#pragma unroll
    for (int mi = 0; mi < 4; ++mi)
      a[mi] = *reinterpret_cast<const bf16x8*>(
          vbf + (size_t)(m0 + wr * 64 + mi * 16 + lr) * 512 + k0 + lg * 8);
#pragma unroll
    for (int ni = 0; ni < 4; ++ni)
      bb[ni] = *reinterpret_cast<const bf16x8*>(
          w1t + (size_t)(n0 + wc * 64 + ni * 16 + lr) * 512 + k0 + lg * 8);
#pragma unroll
    for (int mi = 0; mi < 4; ++mi)
#pragma unroll
      for (int ni = 0; ni < 4; ++ni)
        acc[mi][ni] = __builtin_amdgcn_mfma_f32_16x16x32_bf16(a[mi], bb[ni], acc[mi][ni], 0, 0, 0);
  }
#pragma unroll
  for (int mi = 0; mi < 4; ++mi)
#pragma unroll
    for (int ni = 0; ni < 4; ++ni) {
      int col = n0 + wc * 64 + ni * 16 + lr;
      int h = col >> 7, j = col & 127;
      float bias = b1[col];
#pragma unroll
      for (int r = 0; r < 4; ++r) {
        int row = m0 + wr * 64 + mi * 16 + lg * 4 + r;
        int bb_ = row >> 10, s = row & 1023;
        unsigned short bv = f2bf(acc[mi][ni][r] + bias);
        size_t base = ((size_t)(bb_ * 16 + h) << 16) + (size_t)s * 64;
        if (j < 64) k_ws[base + j] = bv;
        else        q_ws[base + j - 64] = bv;
      }
    }
}

// ---------------- scores: QK^T -> exp (no max-sub) -> attn fp32 + E bf16 + 1/l ----------------
// QBLK=32, 4096 blocks (XCD-swizzled), 512 threads (8 waves); wave w owns cols w*128..+127.
__launch_bounds__(512)
__global__ void scores_kernel(const unsigned short* __restrict__ q_ws,
                              const unsigned short* __restrict__ k_ws,
                              const int* __restrict__ pad,           // [8][1024]
                              float* __restrict__ attn_out,          // [8][16][1024][1024]
                              unsigned short* __restrict__ eb,       // bf16 [128][1024][1024]
                              float* __restrict__ linv_ws) {         // [128][1024]
  const int wg = (blockIdx.x & 7) * 512 + (blockIdx.x >> 3);
  const int qt = wg & 31, h = (wg >> 5) & 15, b = wg >> 9;
  const int bh = b * 16 + h, q0 = qt * 32;
  const int w = threadIdx.x >> 6, l = threadIdx.x & 63;
  const int lr = l & 15, lg = l >> 4;

  __shared__ unsigned short E_lds[32][1032];  // 66KB
  __shared__ float lw[8][32];
  __shared__ float linv_s[32];

  const unsigned short* qb = q_ws + ((size_t)bh << 16);
  const unsigned short* kb = k_ws + ((size_t)bh << 16);
  const int* pmb = pad + b * 1024;

  bf16x8 a_q[2][2];
#pragma unroll
  for (int mf = 0; mf < 2; ++mf)
#pragma unroll
    for (int ks = 0; ks < 2; ++ks)
      a_q[mf][ks] = *reinterpret_cast<const bf16x8*>(
          qb + (size_t)(q0 + mf * 16 + lr) * 64 + ks * 32 + lg * 8);

  float l_run[2][4];
#pragma unroll
  for (int mf = 0; mf < 2; ++mf)
#pragma unroll
    for (int r = 0; r < 4; ++r) l_run[mf][r] = 0.f;

#pragma unroll
  for (int sub = 0; sub < 2; ++sub) {
    const int c0 = w * 128 + sub * 64;
    f32x4 s[2][4];
#pragma unroll
    for (int mf = 0; mf < 2; ++mf)
#pragma unroll
      for (int nf = 0; nf < 4; ++nf) s[mf][nf] = (f32x4){0.f, 0.f, 0.f, 0.f};
#pragma unroll
    for (int ks = 0; ks < 2; ++ks) {
      bf16x8 bk[4];
#pragma unroll
      for (int nf = 0; nf < 4; ++nf)
        bk[nf] = *reinterpret_cast<const bf16x8*>(
            kb + (size_t)(c0 + nf * 16 + lr) * 64 + ks * 32 + lg * 8);
#pragma unroll
      for (int mf = 0; mf < 2; ++mf)
#pragma unroll
        for (int nf = 0; nf < 4; ++nf)
          s[mf][nf] = __builtin_amdgcn_mfma_f32_16x16x32_bf16(a_q[mf][ks], bk[nf], s[mf][nf], 0, 0, 0);
    }
    int msk[4];
#pragma unroll
    for (int nf = 0; nf < 4; ++nf) msk[nf] = pmb[c0 + nf * 16 + lr];
#pragma unroll
    for (int mf = 0; mf < 2; ++mf)
#pragma unroll
      for (int nf = 0; nf < 4; ++nf)
#pragma unroll
        for (int r = 0; r < 4; ++r) {
          float e = msk[nf] ? 0.f : __expf(s[mf][nf][r] * 0.125f);
          l_run[mf][r] += e;
          E_lds[mf * 16 + lg * 4 + r][c0 + nf * 16 + lr] = f2bf(e);
        }
  }

  // row-sum reduce over 16 lr lanes, then cross-wave combine
#pragma unroll
  for (int mf = 0; mf < 2; ++mf)
#pragma unroll
    for (int r = 0; r < 4; ++r) {
      float v = l_run[mf][r];
      v += __shfl_xor(v, 1); v += __shfl_xor(v, 2);
      v += __shfl_xor(v, 4); v += __shfl_xor(v, 8);
      if (lr == 0) lw[w][mf * 16 + lg * 4 + r] = v;
    }
  __syncthreads();
  if (threadIdx.x < 32) {
    float s = 0.f;
#pragma unroll
    for (int ww = 0; ww < 8; ++ww) s += lw[ww][threadIdx.x];
    float li = 1.f / s;
    linv_s[threadIdx.x] = li;
    linv_ws[(size_t)bh * 1024 + q0 + threadIdx.x] = li;
  }
  __syncthreads();

  // write phase: 16 threads/row; lane cb covers cols cb*8 + i*128 -> per-instruction
  // 512B (f32) / 256B (bf16) contiguous segments.
  {
    const int row = threadIdx.x >> 4;
    const int cb = threadIdx.x & 15;
    const float sc = linv_s[row];
    float* rowp = attn_out + ((size_t)bh << 20) + (size_t)(q0 + row) * 1024;
    unsigned short* ebrow = eb + ((size_t)bh << 20) + (size_t)(q0 + row) * 1024;
#pragma unroll
    for (int i = 0; i < 8; ++i) {
      int c8 = cb * 8 + i * 128;
      bf16x8 ev = *reinterpret_cast<const bf16x8*>(&E_lds[row][c8]);
      f32x4 o0, o1;
#pragma unroll
      for (int j = 0; j < 4; ++j) o0[j] = bf2f((unsigned short)ev[j]) * sc;
#pragma unroll
      for (int j = 0; j < 4; ++j) o1[j] = bf2f((unsigned short)ev[4 + j]) * sc;
      *reinterpret_cast<f32x4*>(rowp + c8) = o0;
      *reinterpret_cast<f32x4*>(rowp + c8 + 4) = o1;
      *reinterpret_cast<bf16x8*>(ebrow + c8) = ev;
    }
  }
}

// ---------------- PV: O = E @ V * linv  (BM=256, BN=128, BK=32, 512 threads, dbuf) ----------------
// A = eb bf16 [bh][1024][1024], B = vt bf16 [512][8192]. 2048 blocks XCD-swizzled
// (nt innermost -> A-panel L2 reuse). 8 waves = 4M x 2N, 64x64 output per wave.
__launch_bounds__(512)
__global__ void pv_kernel(const unsigned short* __restrict__ eb,
                          const unsigned short* __restrict__ vt,
                          const float* __restrict__ linv_ws,
                          unsigned short* __restrict__ o_ws) {
  const int wg = (blockIdx.x & 7) * 256 + (blockIdx.x >> 3);
  const int nt = wg & 3, mt = (wg >> 2) & 3, bh = wg >> 4;
  const int b = bh >> 4, h = bh & 15;
  const int m0 = mt * 256, n0 = nt * 128;

  __shared__ unsigned short Asm[2][256 * 32];   // 32KB
  __shared__ unsigned short Bsm[2][128 * 32];   // 16KB
  const int w = threadIdx.x >> 6, l = threadIdx.x & 63;
  const int wr = w >> 1, wc = w & 1, lr = l & 15, lg = l >> 4;

  f32x4 acc[4][4];
#pragma unroll
  for (int mi = 0; mi < 4; ++mi)
#pragma unroll
    for (int ni = 0; ni < 4; ++ni) acc[mi][ni] = (f32x4){0.f, 0.f, 0.f, 0.f};

  const int srow = threadIdx.x >> 2;            // 0..127
  const int scol = (threadIdx.x & 3) * 8;       // 0,8,16,24
  const unsigned short* gA0 = eb + ((size_t)bh << 20) + (size_t)(m0 + srow) * 1024 + scol;
  const unsigned short* gA1 = gA0 + (size_t)128 * 1024;
  const unsigned short* gB0 = vt + (size_t)(n0 + srow) * 8192 + (size_t)b * 1024 + scol;
  const int ldsoff = w * 512;                   // wave-uniform; lane adds l*16B

  // per-row 1/l for the epilogue
  float linv_r[4][4];
  {
    const float* lrow = linv_ws + (size_t)bh * 1024 + m0 + wr * 64 + lg * 4;
#pragma unroll
    for (int mi = 0; mi < 4; ++mi)
#pragma unroll
      for (int r = 0; r < 4; ++r) linv_r[mi][r] = lrow[mi * 16 + r];
  }

  auto STAGE = [&](int buf, int kt) {
    int k0 = kt * 32;
    gload_lds16(gA0 + k0, &Asm[buf][ldsoff]);                  // rows 0..127
    gload_lds16(gA1 + k0, &Asm[buf][128 * 32 + ldsoff]);       // rows 128..255
    gload_lds16(gB0 + k0, &Bsm[buf][ldsoff]);                  // rows 0..127
  };
  auto COMPUTE = [&](int buf) {
    bf16x8 a[4], bb[4];
#pragma unroll
    for (int mi = 0; mi < 4; ++mi)
      a[mi] = *reinterpret_cast<const bf16x8*>(&Asm[buf][(wr * 64 + mi * 16 + lr) * 32 + lg * 8]);
#pragma unroll
    for (int ni = 0; ni < 4; ++ni)
      bb[ni] = *reinterpret_cast<const bf16x8*>(&Bsm[buf][(wc * 64 + ni * 16 + lr) * 32 + lg * 8]);
    __builtin_amdgcn_s_setprio(1);
#pragma unroll
    for (int mi = 0; mi < 4; ++mi)
#pragma unroll
      for (int ni = 0; ni < 4; ++ni)
        acc[mi][ni] = __builtin_amdgcn_mfma_f32_16x16x32_bf16(a[mi], bb[ni], acc[mi][ni], 0, 0, 0);
    __builtin_amdgcn_s_setprio(0);
  };

  STAGE(0, 0);
  __syncthreads();
  int cur = 0;
  for (int kt = 0; kt < 31; ++kt) {
    STAGE(cur ^ 1, kt + 1);   // issue next-tile loads BEFORE compute
    COMPUTE(cur);
    __syncthreads();
    cur ^= 1;
  }
  COMPUTE(cur);

  // epilogue: O tile * linv -> o_ws bf16 [b][s][h*512+c]
#pragma unroll
  for (int mi = 0; mi < 4; ++mi)
#pragma unroll
    for (int ni = 0; ni < 4; ++ni)
#pragma unroll
      for (int r = 0; r < 4; ++r) {
        int row = m0 + wr * 64 + mi * 16 + lg * 4 + r;
        int col = n0 + wc * 64 + ni * 16 + lr;
        o_ws[(size_t)(b * 1024 + row) * 8192 + h * 512 + col] =
            f2bf(acc[mi][ni][r] * linv_r[mi][r]);
      }
}

// ---------------- GEMM2: y = o @ W2 + b2  (BM=64, BN=128, BK=32, dbuf, 512 blocks) ----------------
// flat grid XCD-swizzled, nt INNER: A-panel read once, W2 panels cycle in L2.
__launch_bounds__(256)
__global__ void gemm2_kernel(const unsigned short* __restrict__ o_ws,
                             const unsigned short* __restrict__ w2t,
                             const float* __restrict__ b2,
                             float* __restrict__ y) {
  const int wg = (blockIdx.x & 7) * 64 + (blockIdx.x >> 3);
  const int nt = wg & 3, mt = wg >> 2;
  const int m0 = mt * 64, n0 = nt * 128;

  __shared__ unsigned short As[2][64 * 32];
  __shared__ unsigned short Bs[2][128 * 32];
  const int w = threadIdx.x >> 6, l = threadIdx.x & 63;
  const int wr = w >> 1, wc = w & 1, lr = l & 15, lg = l >> 4;

  f32x4 acc[2][4];
#pragma unroll
  for (int mi = 0; mi < 2; ++mi)
#pragma unroll
    for (int ni = 0; ni < 4; ++ni) acc[mi][ni] = (f32x4){0.f, 0.f, 0.f, 0.f};

  const int srow = threadIdx.x >> 2;        // 0..63
  const int scol = (threadIdx.x & 3) * 8;   // 0,8,16,24
  const unsigned short* gA  = o_ws + (size_t)(m0 + srow) * 8192 + scol;
  const unsigned short* gB0 = w2t + (size_t)(n0 + srow) * 8192 + scol;
  const unsigned short* gB1 = gB0 + (size_t)64 * 8192;
  const int ldsoff = w * 512;

  auto STAGE = [&](int buf, int kt) {
    int k0 = kt * 32;
    gload_lds16(gA + k0, &As[buf][ldsoff]);
    gload_lds16(gB0 + k0, &Bs[buf][ldsoff]);
    gload_lds16(gB1 + k0, &Bs[buf][64 * 32 + ldsoff]);
  };

  auto COMPUTE = [&](int buf) {
    bf16x8 a[2], bb[4];
#pragma unroll
    for (int mi = 0; mi < 2; ++mi)
      a[mi] = *reinterpret_cast<const bf16x8*>(&As[buf][(wr * 32 + mi * 16 + lr) * 32 + lg * 8]);
#pragma unroll
    for (int ni = 0; ni < 4; ++ni)
      bb[ni] = *reinterpret_cast<const bf16x8*>(&Bs[buf][(wc * 64 + ni * 16 + lr) * 32 + lg * 8]);
    __builtin_amdgcn_s_setprio(1);
#pragma unroll
    for (int mi = 0; mi < 2; ++mi)
#pragma unroll
      for (int ni = 0; ni < 4; ++ni)
        acc[mi][ni] = __builtin_amdgcn_mfma_f32_16x16x32_bf16(a[mi], bb[ni], acc[mi][ni], 0, 0, 0);
    __builtin_amdgcn_s_setprio(0);
  };

  STAGE(0, 0);
  __syncthreads();
  int cur = 0;
  for (int kt = 0; kt < 255; ++kt) {
    STAGE(cur ^ 1, kt + 1);
    COMPUTE(cur);
    __syncthreads();
    cur ^= 1;
  }
  COMPUTE(cur);

#pragma unroll
  for (int mi = 0; mi < 2; ++mi)
#pragma unroll
    for (int ni = 0; ni < 4; ++ni) {
      int col = n0 + wc * 64 + ni * 16 + lr;
      float bias = b2[col];
#pragma unroll
      for (int r = 0; r < 4; ++r)
        y[(size_t)(m0 + wr * 32 + mi * 16 + lg * 4 + r) * 512 + col] = acc[mi][ni][r] + bias;
    }
}

// ---------------- launch ----------------
extern "C" void kernel_launch(void* const* d_in, const int* in_sizes, int n_in,
                              void* d_out, int out_size, void* d_ws, size_t ws_size,
                              hipStream_t stream) {
  const float* v   = (const float*)d_in[0];
  const int*   pad = (const int*)d_in[1];
  const float* W1  = (const float*)d_in[2];
  const float* b1  = (const float*)d_in[3];
  const float* W2  = (const float*)d_in[4];
  const float* b2  = (const float*)d_in[5];
  float* out  = (float*)d_out;
  float* attn = out + (size_t)8 * 1024 * 512;

  char* ws = (char*)d_ws;
  unsigned short* w1t  = (unsigned short*)(ws);               //   2 MB  [2048][512]
  unsigned short* w2t  = (unsigned short*)(ws + 2097152);     //   8 MB  [512][8192]
  unsigned short* vt   = (unsigned short*)(ws + 10485760);    //   8 MB  [512][8192]
  unsigned short* vbf  = (unsigned short*)(ws + 18874368);    //   8 MB  [8192][512]
  unsigned short* q_ws = (unsigned short*)(ws + 27262976);    //  16 MB  [128][1024][64]
  unsigned short* k_ws = (unsigned short*)(ws + 44040192);    //  16 MB  [128][1024][64]
  unsigned short* o_ws = (unsigned short*)(ws + 60817408);    // 134 MB  [8192][8192]
  unsigned short* eb   = (unsigned short*)(ws + 195035136);   // 268 MB  [128][1024][1024]
  float*          linv = (float*)(ws + 463470592);            // 0.5 MB  [128][1024]

  transpose_cvt_kernel<<<dim3(64, 16), 256, 0, stream>>>(W1, w1t, 512, 2048);
  transpose_cvt_kernel<<<dim3(16, 256), 256, 0, stream>>>(W2, w2t, 8192, 512);
  transpose_cvt_kernel<<<dim3(16, 256), 256, 0, stream>>>(v, vt, 8192, 512);
  cvt_bf16_kernel<<<4096, 256, 0, stream>>>(v, vbf, 1048576);
  gemm1_kernel<<<dim3(16, 64), 256, 0, stream>>>(vbf, w1t, b1, q_ws, k_ws);
  scores_kernel<<<4096, 512, 0, stream>>>(q_ws, k_ws, pad, attn, eb, linv);
  pv_kernel<<<2048, 512, 0, stream>>>(eb, vt, linv, o_ws);
  gemm2_kernel<<<512, 256, 0, stream>>>(o_ws, w2t, b2, out);
}

// Round 15
// 686.688 us; speedup vs baseline: 1.0843x; 1.0843x over previous
//
#include <hip/hip_runtime.h>

// MultiHeadAttention: v(8,1024,512) fp32, pad(8,1,1,1024) int, W1(512,2048), b1(2048),
// W2(8192,512), b2(512) -> out (8,1024,512) fp32 ++ attn (8,16,1024,1024) fp32.
// All matmuls in bf16 MFMA 16x16x32, fp32 accumulate.
// R15: exact R11 revert (best verified, 690us) + prep_v fusion (v read once ->
//      vbf + vt in a single kernel; one fewer launch, -16MB of reads).

typedef __attribute__((ext_vector_type(8))) short bf16x8;
typedef __attribute__((ext_vector_type(4))) float f32x4;
typedef __attribute__((ext_vector_type(4))) unsigned short u16x4;

__device__ __forceinline__ unsigned short f2bf(float f) {
  unsigned u = __builtin_bit_cast(unsigned, f);
  u += 0x7FFFu + ((u >> 16) & 1u);   // RTN-even
  return (unsigned short)(u >> 16);
}
__device__ __forceinline__ float bf2f(unsigned short u) {
  return __builtin_bit_cast(float, (unsigned)u << 16);
}

__device__ __forceinline__ void gload_lds16(const unsigned short* g, unsigned short* l) {
  __builtin_amdgcn_global_load_lds(
      (const __attribute__((address_space(1))) unsigned int*)(g),
      (__attribute__((address_space(3))) unsigned int*)(l), 16, 0, 0);
}

// ---------------- preprocessing ----------------

// W transpose: in fp32 [R][C] -> out bf16 [C][R]
__global__ void transpose_cvt_kernel(const float* __restrict__ in,
                                     unsigned short* __restrict__ out,
                                     int R, int C) {
  __shared__ float tile[32][33];
  int c0 = blockIdx.x * 32, r0 = blockIdx.y * 32;
  int tx = threadIdx.x & 31, ty = threadIdx.x >> 5;
#pragma unroll
  for (int i = ty; i < 32; i += 8)
    tile[i][tx] = in[(size_t)(r0 + i) * C + (c0 + tx)];
  __syncthreads();
#pragma unroll
  for (int i = ty; i < 32; i += 8)
    out[(size_t)(c0 + i) * R + (r0 + tx)] = f2bf(tile[tx][i]);
}

// v fused prep: read v [8192][512] fp32 once; emit vbf (same layout bf16) and
// vt [512][8192] bf16 (transposed). grid (16, 256), 256 threads.
__global__ void prep_v_kernel(const float* __restrict__ v,
                              unsigned short* __restrict__ vbf,
                              unsigned short* __restrict__ vt) {
  __shared__ float tile[32][33];
  int c0 = blockIdx.x * 32, r0 = blockIdx.y * 32;
  int tx = threadIdx.x & 31, ty = threadIdx.x >> 5;
#pragma unroll
  for (int i = ty; i < 32; i += 8) {
    float val = v[(size_t)(r0 + i) * 512 + (c0 + tx)];
    tile[i][tx] = val;
    vbf[(size_t)(r0 + i) * 512 + (c0 + tx)] = f2bf(val);
  }
  __syncthreads();
#pragma unroll
  for (int i = ty; i < 32; i += 8)
    vt[(size_t)(c0 + i) * 8192 + (r0 + tx)] = f2bf(tile[tx][i]);
}

// ---------------- GEMM1: kq = v @ W1 + b1 ----------------
__launch_bounds__(256)
__global__ void gemm1_kernel(const unsigned short* __restrict__ vbf,
                             const unsigned short* __restrict__ w1t,
                             const float* __restrict__ b1,
                             unsigned short* __restrict__ q_ws,
                             unsigned short* __restrict__ k_ws) {
  const int m0 = blockIdx.y * 128, n0 = blockIdx.x * 128;
  const int w = threadIdx.x >> 6, l = threadIdx.x & 63;
  const int wr = w >> 1, wc = w & 1, lr = l & 15, lg = l >> 4;
  f32x4 acc[4][4];
#pragma unroll
  for (int mi = 0; mi < 4; ++mi)
#pragma unroll
    for (int ni = 0; ni < 4; ++ni) acc[mi][ni] = (f32x4){0.f, 0.f, 0.f, 0.f};

  for (int k0 = 0; k0 < 512; k0 += 32) {
    bf16x8 a[4], bb[4];
#pragma unroll
    for (int mi = 0; mi < 4; ++mi)
      a[mi] = *reinterpret_cast<const bf16x8*>(
          vbf + (size_t)(m0 + wr * 64 + mi * 16 + lr) * 512 + k0 + lg * 8);
#pragma unroll
    for (int ni = 0; ni < 4; ++ni)
      bb[ni] = *reinterpret_cast<const bf16x8*>(
          w1t + (size_t)(n0 + wc * 64 + ni * 16 + lr) * 512 + k0 + lg * 8);
#pragma unroll
    for (int mi = 0; mi < 4; ++mi)
#pragma unroll
      for (int ni = 0; ni < 4; ++ni)
        acc[mi][ni] = __builtin_amdgcn_mfma_f32_16x16x32_bf16(a[mi], bb[ni], acc[mi][ni], 0, 0, 0);
  }
#pragma unroll
  for (int mi = 0; mi < 4; ++mi)
#pragma unroll
    for (int ni = 0; ni < 4; ++ni) {
      int col = n0 + wc * 64 + ni * 16 + lr;
      int h = col >> 7, j = col & 127;
      float bias = b1[col];
#pragma unroll
      for (int r = 0; r < 4; ++r) {
        int row = m0 + wr * 64 + mi * 16 + lg * 4 + r;
        int bb_ = row >> 10, s = row & 1023;
        unsigned short bv = f2bf(acc[mi][ni][r] + bias);
        size_t base = ((size_t)(bb_ * 16 + h) << 16) + (size_t)s * 64;
        if (j < 64) k_ws[base + j] = bv;
        else        q_ws[base + j - 64] = bv;
      }
    }
}

// ---------------- scores: QK^T -> exp (no max-sub) -> attn fp32 + E bf16 + 1/l ----------------
// QBLK=32, 4096 blocks (XCD-swizzled), 512 threads (8 waves); wave w owns cols w*128..+127.
__launch_bounds__(512)
__global__ void scores_kernel(const unsigned short* __restrict__ q_ws,
                              const unsigned short* __restrict__ k_ws,
                              const int* __restrict__ pad,           // [8][1024]
                              float* __restrict__ attn_out,          // [8][16][1024][1024]
                              unsigned short* __restrict__ eb,       // bf16 [128][1024][1024]
                              float* __restrict__ linv_ws) {         // [128][1024]
  const int wg = (blockIdx.x & 7) * 512 + (blockIdx.x >> 3);
  const int qt = wg & 31, h = (wg >> 5) & 15, b = wg >> 9;
  const int bh = b * 16 + h, q0 = qt * 32;
  const int w = threadIdx.x >> 6, l = threadIdx.x & 63;
  const int lr = l & 15, lg = l >> 4;

  __shared__ unsigned short E_lds[32][1032];  // 66KB
  __shared__ float lw[8][32];
  __shared__ float linv_s[32];

  const unsigned short* qb = q_ws + ((size_t)bh << 16);
  const unsigned short* kb = k_ws + ((size_t)bh << 16);
  const int* pmb = pad + b * 1024;

  bf16x8 a_q[2][2];
#pragma unroll
  for (int mf = 0; mf < 2; ++mf)
#pragma unroll
    for (int ks = 0; ks < 2; ++ks)
      a_q[mf][ks] = *reinterpret_cast<const bf16x8*>(
          qb + (size_t)(q0 + mf * 16 + lr) * 64 + ks * 32 + lg * 8);

  float l_run[2][4];
#pragma unroll
  for (int mf = 0; mf < 2; ++mf)
#pragma unroll
    for (int r = 0; r < 4; ++r) l_run[mf][r] = 0.f;

#pragma unroll
  for (int sub = 0; sub < 2; ++sub) {
    const int c0 = w * 128 + sub * 64;
    f32x4 s[2][4];
#pragma unroll
    for (int mf = 0; mf < 2; ++mf)
#pragma unroll
      for (int nf = 0; nf < 4; ++nf) s[mf][nf] = (f32x4){0.f, 0.f, 0.f, 0.f};
#pragma unroll
    for (int ks = 0; ks < 2; ++ks) {
      bf16x8 bk[4];
#pragma unroll
      for (int nf = 0; nf < 4; ++nf)
        bk[nf] = *reinterpret_cast<const bf16x8*>(
            kb + (size_t)(c0 + nf * 16 + lr) * 64 + ks * 32 + lg * 8);
#pragma unroll
      for (int mf = 0; mf < 2; ++mf)
#pragma unroll
        for (int nf = 0; nf < 4; ++nf)
          s[mf][nf] = __builtin_amdgcn_mfma_f32_16x16x32_bf16(a_q[mf][ks], bk[nf], s[mf][nf], 0, 0, 0);
    }
    int msk[4];
#pragma unroll
    for (int nf = 0; nf < 4; ++nf) msk[nf] = pmb[c0 + nf * 16 + lr];
#pragma unroll
    for (int mf = 0; mf < 2; ++mf)
#pragma unroll
      for (int nf = 0; nf < 4; ++nf)
#pragma unroll
        for (int r = 0; r < 4; ++r) {
          float e = msk[nf] ? 0.f : __expf(s[mf][nf][r] * 0.125f);
          l_run[mf][r] += e;
          E_lds[mf * 16 + lg * 4 + r][c0 + nf * 16 + lr] = f2bf(e);
        }
  }

  // row-sum reduce over 16 lr lanes, then cross-wave combine
#pragma unroll
  for (int mf = 0; mf < 2; ++mf)
#pragma unroll
    for (int r = 0; r < 4; ++r) {
      float v = l_run[mf][r];
      v += __shfl_xor(v, 1); v += __shfl_xor(v, 2);
      v += __shfl_xor(v, 4); v += __shfl_xor(v, 8);
      if (lr == 0) lw[w][mf * 16 + lg * 4 + r] = v;
    }
  __syncthreads();
  if (threadIdx.x < 32) {
    float s = 0.f;
#pragma unroll
    for (int ww = 0; ww < 8; ++ww) s += lw[ww][threadIdx.x];
    float li = 1.f / s;
    linv_s[threadIdx.x] = li;
    linv_ws[(size_t)bh * 1024 + q0 + threadIdx.x] = li;
  }
  __syncthreads();

  // write phase: 16 threads/row; lane cb covers cols cb*8 + i*128 -> per-instruction
  // 512B (f32) / 256B (bf16) contiguous segments.
  {
    const int row = threadIdx.x >> 4;
    const int cb = threadIdx.x & 15;
    const float sc = linv_s[row];
    float* rowp = attn_out + ((size_t)bh << 20) + (size_t)(q0 + row) * 1024;
    unsigned short* ebrow = eb + ((size_t)bh << 20) + (size_t)(q0 + row) * 1024;
#pragma unroll
    for (int i = 0; i < 8; ++i) {
      int c8 = cb * 8 + i * 128;
      bf16x8 ev = *reinterpret_cast<const bf16x8*>(&E_lds[row][c8]);
      f32x4 o0, o1;
#pragma unroll
      for (int j = 0; j < 4; ++j) o0[j] = bf2f((unsigned short)ev[j]) * sc;
#pragma unroll
      for (int j = 0; j < 4; ++j) o1[j] = bf2f((unsigned short)ev[4 + j]) * sc;
      *reinterpret_cast<f32x4*>(rowp + c8) = o0;
      *reinterpret_cast<f32x4*>(rowp + c8 + 4) = o1;
      *reinterpret_cast<bf16x8*>(ebrow + c8) = ev;
    }
  }
}

// ---------------- PV: O = E @ V * linv  (pure gload_lds dbuf GEMM) ----------------
// A = eb bf16 [bh][1024][1024], B = vt bf16 [512][8192]. BM=BN=128, BK=32, K=1024.
// 4096 flat blocks XCD-swizzled (nt innermost -> A-panel L2 reuse), 256 threads.
__launch_bounds__(256)
__global__ void pv_kernel(const unsigned short* __restrict__ eb,
                          const unsigned short* __restrict__ vt,
                          const float* __restrict__ linv_ws,
                          unsigned short* __restrict__ o_ws) {
  const int wg = (blockIdx.x & 7) * 512 + (blockIdx.x >> 3);
  const int nt = wg & 3, mt = (wg >> 2) & 7, bh = wg >> 5;
  const int b = bh >> 4, h = bh & 15;
  const int m0 = mt * 128, n0 = nt * 128;

  __shared__ unsigned short Asm[2][128 * 32];
  __shared__ unsigned short Bsm[2][128 * 32];
  const int w = threadIdx.x >> 6, l = threadIdx.x & 63;
  const int wr = w >> 1, wc = w & 1, lr = l & 15, lg = l >> 4;

  f32x4 acc[4][4];
#pragma unroll
  for (int mi = 0; mi < 4; ++mi)
#pragma unroll
    for (int ni = 0; ni < 4; ++ni) acc[mi][ni] = (f32x4){0.f, 0.f, 0.f, 0.f};

  const int srow = threadIdx.x >> 2;            // 0..63
  const int scol = (threadIdx.x & 3) * 8;       // 0,8,16,24
  const unsigned short* gA0 = eb + ((size_t)bh << 20) + (size_t)(m0 + srow) * 1024 + scol;
  const unsigned short* gA1 = gA0 + (size_t)64 * 1024;
  const unsigned short* gB0 = vt + (size_t)(n0 + srow) * 8192 + (size_t)b * 1024 + scol;
  const unsigned short* gB1 = gB0 + (size_t)64 * 8192;
  const int ldsoff = w * 512;

  // per-row 1/l for the epilogue
  float linv_r[4][4];
  {
    const float* lrow = linv_ws + (size_t)bh * 1024 + m0 + wr * 64 + lg * 4;
#pragma unroll
    for (int mi = 0; mi < 4; ++mi)
#pragma unroll
      for (int r = 0; r < 4; ++r) linv_r[mi][r] = lrow[mi * 16 + r];
  }

  auto STAGE = [&](int buf, int kt) {
    int k0 = kt * 32;
    gload_lds16(gA0 + k0, &Asm[buf][ldsoff]);
    gload_lds16(gA1 + k0, &Asm[buf][64 * 32 + ldsoff]);
    gload_lds16(gB0 + k0, &Bsm[buf][ldsoff]);
    gload_lds16(gB1 + k0, &Bsm[buf][64 * 32 + ldsoff]);
  };
  auto COMPUTE = [&](int buf) {
    bf16x8 a[4], bb[4];
#pragma unroll
    for (int mi = 0; mi < 4; ++mi)
      a[mi] = *reinterpret_cast<const bf16x8*>(&Asm[buf][(wr * 64 + mi * 16 + lr) * 32 + lg * 8]);
#pragma unroll
    for (int ni = 0; ni < 4; ++ni)
      bb[ni] = *reinterpret_cast<const bf16x8*>(&Bsm[buf][(wc * 64 + ni * 16 + lr) * 32 + lg * 8]);
    __builtin_amdgcn_s_setprio(1);
#pragma unroll
    for (int mi = 0; mi < 4; ++mi)
#pragma unroll
      for (int ni = 0; ni < 4; ++ni)
        acc[mi][ni] = __builtin_amdgcn_mfma_f32_16x16x32_bf16(a[mi], bb[ni], acc[mi][ni], 0, 0, 0);
    __builtin_amdgcn_s_setprio(0);
  };

  STAGE(0, 0);
  __syncthreads();
  int cur = 0;
  for (int kt = 0; kt < 31; ++kt) {
    STAGE(cur ^ 1, kt + 1);   // issue next-tile loads BEFORE compute
    COMPUTE(cur);
    __syncthreads();
    cur ^= 1;
  }
  COMPUTE(cur);

  // epilogue: O tile * linv -> o_ws bf16 [b][s][h*512+c]
#pragma unroll
  for (int mi = 0; mi < 4; ++mi)
#pragma unroll
    for (int ni = 0; ni < 4; ++ni)
#pragma unroll
      for (int r = 0; r < 4; ++r) {
        int row = m0 + wr * 64 + mi * 16 + lg * 4 + r;
        int col = n0 + wc * 64 + ni * 16 + lr;
        o_ws[(size_t)(b * 1024 + row) * 8192 + h * 512 + col] =
            f2bf(acc[mi][ni][r] * linv_r[mi][r]);
      }
}

// ---------------- GEMM2: y = o @ W2 + b2  (BM=64, BN=128, BK=32, dbuf, 512 blocks) ----------------
// flat grid XCD-swizzled, nt INNER: A-panel read once, W2 panels cycle in L2.
__launch_bounds__(256)
__global__ void gemm2_kernel(const unsigned short* __restrict__ o_ws,
                             const unsigned short* __restrict__ w2t,
                             const float* __restrict__ b2,
                             float* __restrict__ y) {
  const int wg = (blockIdx.x & 7) * 64 + (blockIdx.x >> 3);
  const int nt = wg & 3, mt = wg >> 2;
  const int m0 = mt * 64, n0 = nt * 128;

  __shared__ unsigned short As[2][64 * 32];
  __shared__ unsigned short Bs[2][128 * 32];
  const int w = threadIdx.x >> 6, l = threadIdx.x & 63;
  const int wr = w >> 1, wc = w & 1, lr = l & 15, lg = l >> 4;

  f32x4 acc[2][4];
#pragma unroll
  for (int mi = 0; mi < 2; ++mi)
#pragma unroll
    for (int ni = 0; ni < 4; ++ni) acc[mi][ni] = (f32x4){0.f, 0.f, 0.f, 0.f};

  const int srow = threadIdx.x >> 2;        // 0..63
  const int scol = (threadIdx.x & 3) * 8;   // 0,8,16,24
  const unsigned short* gA  = o_ws + (size_t)(m0 + srow) * 8192 + scol;
  const unsigned short* gB0 = w2t + (size_t)(n0 + srow) * 8192 + scol;
  const unsigned short* gB1 = gB0 + (size_t)64 * 8192;
  const int ldsoff = w * 512;

  auto STAGE = [&](int buf, int kt) {
    int k0 = kt * 32;
    gload_lds16(gA + k0, &As[buf][ldsoff]);
    gload_lds16(gB0 + k0, &Bs[buf][ldsoff]);
    gload_lds16(gB1 + k0, &Bs[buf][64 * 32 + ldsoff]);
  };

  auto COMPUTE = [&](int buf) {
    bf16x8 a[2], bb[4];
#pragma unroll
    for (int mi = 0; mi < 2; ++mi)
      a[mi] = *reinterpret_cast<const bf16x8*>(&As[buf][(wr * 32 + mi * 16 + lr) * 32 + lg * 8]);
#pragma unroll
    for (int ni = 0; ni < 4; ++ni)
      bb[ni] = *reinterpret_cast<const bf16x8*>(&Bs[buf][(wc * 64 + ni * 16 + lr) * 32 + lg * 8]);
    __builtin_amdgcn_s_setprio(1);
#pragma unroll
    for (int mi = 0; mi < 2; ++mi)
#pragma unroll
      for (int ni = 0; ni < 4; ++ni)
        acc[mi][ni] = __builtin_amdgcn_mfma_f32_16x16x32_bf16(a[mi], bb[ni], acc[mi][ni], 0, 0, 0);
    __builtin_amdgcn_s_setprio(0);
  };

  STAGE(0, 0);
  __syncthreads();
  int cur = 0;
  for (int kt = 0; kt < 255; ++kt) {
    STAGE(cur ^ 1, kt + 1);
    COMPUTE(cur);
    __syncthreads();
    cur ^= 1;
  }
  COMPUTE(cur);

#pragma unroll
  for (int mi = 0; mi < 2; ++mi)
#pragma unroll
    for (int ni = 0; ni < 4; ++ni) {
      int col = n0 + wc * 64 + ni * 16 + lr;
      float bias = b2[col];
#pragma unroll
      for (int r = 0; r < 4; ++r)
        y[(size_t)(m0 + wr * 32 + mi * 16 + lg * 4 + r) * 512 + col] = acc[mi][ni][r] + bias;
    }
}

// ---------------- launch ----------------
extern "C" void kernel_launch(void* const* d_in, const int* in_sizes, int n_in,
                              void* d_out, int out_size, void* d_ws, size_t ws_size,
                              hipStream_t stream) {
  const float* v   = (const float*)d_in[0];
  const int*   pad = (const int*)d_in[1];
  const float* W1  = (const float*)d_in[2];
  const float* b1  = (const float*)d_in[3];
  const float* W2  = (const float*)d_in[4];
  const float* b2  = (const float*)d_in[5];
  float* out  = (float*)d_out;
  float* attn = out + (size_t)8 * 1024 * 512;

  char* ws = (char*)d_ws;
  unsigned short* w1t  = (unsigned short*)(ws);               //   2 MB  [2048][512]
  unsigned short* w2t  = (unsigned short*)(ws + 2097152);     //   8 MB  [512][8192]
  unsigned short* vt   = (unsigned short*)(ws + 10485760);    //   8 MB  [512][8192]
  unsigned short* vbf  = (unsigned short*)(ws + 18874368);    //   8 MB  [8192][512]
  unsigned short* q_ws = (unsigned short*)(ws + 27262976);    //  16 MB  [128][1024][64]
  unsigned short* k_ws = (unsigned short*)(ws + 44040192);    //  16 MB  [128][1024][64]
  unsigned short* o_ws = (unsigned short*)(ws + 60817408);    // 134 MB  [8192][8192]
  unsigned short* eb   = (unsigned short*)(ws + 195035136);   // 268 MB  [128][1024][1024]
  float*          linv = (float*)(ws + 463470592);            // 0.5 MB  [128][1024]

  transpose_cvt_kernel<<<dim3(64, 16), 256, 0, stream>>>(W1, w1t, 512, 2048);
  transpose_cvt_kernel<<<dim3(16, 256), 256, 0, stream>>>(W2, w2t, 8192, 512);
  prep_v_kernel<<<dim3(16, 256), 256, 0, stream>>>(v, vbf, vt);
  gemm1_kernel<<<dim3(16, 64), 256, 0, stream>>>(vbf, w1t, b1, q_ws, k_ws);
  scores_kernel<<<4096, 512, 0, stream>>>(q_ws, k_ws, pad, attn, eb, linv);
  pv_kernel<<<4096, 256, 0, stream>>>(eb, vt, linv, o_ws);
  gemm2_kernel<<<512, 256, 0, stream>>>(o_ws, w2t, b2, out);
}

// Round 16
// 675.214 us; speedup vs baseline: 1.1027x; 1.0170x over previous
//
#include <hip/hip_runtime.h>

// MultiHeadAttention: v(8,1024,512) fp32, pad(8,1,1,1024) int, W1(512,2048), b1(2048),
// W2(8192,512), b2(512) -> out (8,1024,512) fp32 ++ attn (8,16,1024,1024) fp32.
// All matmuls in bf16 MFMA 16x16x32, fp32 accumulate.
// R16: pv + gemm2 -> 3-buffer counted-vmcnt pipeline (T4): raw s_barrier, never
//      vmcnt(0) in steady state; loads stay in flight across barriers.

typedef __attribute__((ext_vector_type(8))) short bf16x8;
typedef __attribute__((ext_vector_type(4))) float f32x4;
typedef __attribute__((ext_vector_type(4))) unsigned short u16x4;

__device__ __forceinline__ unsigned short f2bf(float f) {
  unsigned u = __builtin_bit_cast(unsigned, f);
  u += 0x7FFFu + ((u >> 16) & 1u);   // RTN-even
  return (unsigned short)(u >> 16);
}
__device__ __forceinline__ float bf2f(unsigned short u) {
  return __builtin_bit_cast(float, (unsigned)u << 16);
}

__device__ __forceinline__ void gload_lds16(const unsigned short* g, unsigned short* l) {
  __builtin_amdgcn_global_load_lds(
      (const __attribute__((address_space(1))) unsigned int*)(g),
      (__attribute__((address_space(3))) unsigned int*)(l), 16, 0, 0);
}

#define WAITV(N) do { asm volatile("s_waitcnt vmcnt(" #N ")" ::: "memory"); \
                      __builtin_amdgcn_sched_barrier(0); } while (0)
#define BAR()    do { __builtin_amdgcn_s_barrier(); \
                      __builtin_amdgcn_sched_barrier(0); } while (0)

// ---------------- preprocessing ----------------

// W transpose: in fp32 [R][C] -> out bf16 [C][R]
__global__ void transpose_cvt_kernel(const float* __restrict__ in,
                                     unsigned short* __restrict__ out,
                                     int R, int C) {
  __shared__ float tile[32][33];
  int c0 = blockIdx.x * 32, r0 = blockIdx.y * 32;
  int tx = threadIdx.x & 31, ty = threadIdx.x >> 5;
#pragma unroll
  for (int i = ty; i < 32; i += 8)
    tile[i][tx] = in[(size_t)(r0 + i) * C + (c0 + tx)];
  __syncthreads();
#pragma unroll
  for (int i = ty; i < 32; i += 8)
    out[(size_t)(c0 + i) * R + (r0 + tx)] = f2bf(tile[tx][i]);
}

// v fused prep: read v [8192][512] fp32 once; emit vbf (same layout bf16) and
// vt [512][8192] bf16 (transposed). grid (16, 256), 256 threads.
__global__ void prep_v_kernel(const float* __restrict__ v,
                              unsigned short* __restrict__ vbf,
                              unsigned short* __restrict__ vt) {
  __shared__ float tile[32][33];
  int c0 = blockIdx.x * 32, r0 = blockIdx.y * 32;
  int tx = threadIdx.x & 31, ty = threadIdx.x >> 5;
#pragma unroll
  for (int i = ty; i < 32; i += 8) {
    float val = v[(size_t)(r0 + i) * 512 + (c0 + tx)];
    tile[i][tx] = val;
    vbf[(size_t)(r0 + i) * 512 + (c0 + tx)] = f2bf(val);
  }
  __syncthreads();
#pragma unroll
  for (int i = ty; i < 32; i += 8)
    vt[(size_t)(c0 + i) * 8192 + (r0 + tx)] = f2bf(tile[tx][i]);
}

// ---------------- GEMM1: kq = v @ W1 + b1 ----------------
__launch_bounds__(256)
__global__ void gemm1_kernel(const unsigned short* __restrict__ vbf,
                             const unsigned short* __restrict__ w1t,
                             const float* __restrict__ b1,
                             unsigned short* __restrict__ q_ws,
                             unsigned short* __restrict__ k_ws) {
  const int m0 = blockIdx.y * 128, n0 = blockIdx.x * 128;
  const int w = threadIdx.x >> 6, l = threadIdx.x & 63;
  const int wr = w >> 1, wc = w & 1, lr = l & 15, lg = l >> 4;
  f32x4 acc[4][4];
#pragma unroll
  for (int mi = 0; mi < 4; ++mi)
#pragma unroll
    for (int ni = 0; ni < 4; ++ni) acc[mi][ni] = (f32x4){0.f, 0.f, 0.f, 0.f};

  for (int k0 = 0; k0 < 512; k0 += 32) {
    bf16x8 a[4], bb[4];
#pragma unroll
    for (int mi = 0; mi < 4; ++mi)
      a[mi] = *reinterpret_cast<const bf16x8*>(
          vbf + (size_t)(m0 + wr * 64 + mi * 16 + lr) * 512 + k0 + lg * 8);
#pragma unroll
    for (int ni = 0; ni < 4; ++ni)
      bb[ni] = *reinterpret_cast<const bf16x8*>(
          w1t + (size_t)(n0 + wc * 64 + ni * 16 + lr) * 512 + k0 + lg * 8);
#pragma unroll
    for (int mi = 0; mi < 4; ++mi)
#pragma unroll
      for (int ni = 0; ni < 4; ++ni)
        acc[mi][ni] = __builtin_amdgcn_mfma_f32_16x16x32_bf16(a[mi], bb[ni], acc[mi][ni], 0, 0, 0);
  }
#pragma unroll
  for (int mi = 0; mi < 4; ++mi)
#pragma unroll
    for (int ni = 0; ni < 4; ++ni) {
      int col = n0 + wc * 64 + ni * 16 + lr;
      int h = col >> 7, j = col & 127;
      float bias = b1[col];
#pragma unroll
      for (int r = 0; r < 4; ++r) {
        int row = m0 + wr * 64 + mi * 16 + lg * 4 + r;
        int bb_ = row >> 10, s = row & 1023;
        unsigned short bv = f2bf(acc[mi][ni][r] + bias);
        size_t base = ((size_t)(bb_ * 16 + h) << 16) + (size_t)s * 64;
        if (j < 64) k_ws[base + j] = bv;
        else        q_ws[base + j - 64] = bv;
      }
    }
}

// ---------------- scores: QK^T -> exp (no max-sub) -> attn fp32 + E bf16 + 1/l ----------------
// QBLK=32, 4096 blocks (XCD-swizzled), 512 threads (8 waves); wave w owns cols w*128..+127.
__launch_bounds__(512)
__global__ void scores_kernel(const unsigned short* __restrict__ q_ws,
                              const unsigned short* __restrict__ k_ws,
                              const int* __restrict__ pad,           // [8][1024]
                              float* __restrict__ attn_out,          // [8][16][1024][1024]
                              unsigned short* __restrict__ eb,       // bf16 [128][1024][1024]
                              float* __restrict__ linv_ws) {         // [128][1024]
  const int wg = (blockIdx.x & 7) * 512 + (blockIdx.x >> 3);
  const int qt = wg & 31, h = (wg >> 5) & 15, b = wg >> 9;
  const int bh = b * 16 + h, q0 = qt * 32;
  const int w = threadIdx.x >> 6, l = threadIdx.x & 63;
  const int lr = l & 15, lg = l >> 4;

  __shared__ unsigned short E_lds[32][1032];  // 66KB
  __shared__ float lw[8][32];
  __shared__ float linv_s[32];

  const unsigned short* qb = q_ws + ((size_t)bh << 16);
  const unsigned short* kb = k_ws + ((size_t)bh << 16);
  const int* pmb = pad + b * 1024;

  bf16x8 a_q[2][2];
#pragma unroll
  for (int mf = 0; mf < 2; ++mf)
#pragma unroll
    for (int ks = 0; ks < 2; ++ks)
      a_q[mf][ks] = *reinterpret_cast<const bf16x8*>(
          qb + (size_t)(q0 + mf * 16 + lr) * 64 + ks * 32 + lg * 8);

  float l_run[2][4];
#pragma unroll
  for (int mf = 0; mf < 2; ++mf)
#pragma unroll
    for (int r = 0; r < 4; ++r) l_run[mf][r] = 0.f;

#pragma unroll
  for (int sub = 0; sub < 2; ++sub) {
    const int c0 = w * 128 + sub * 64;
    f32x4 s[2][4];
#pragma unroll
    for (int mf = 0; mf < 2; ++mf)
#pragma unroll
      for (int nf = 0; nf < 4; ++nf) s[mf][nf] = (f32x4){0.f, 0.f, 0.f, 0.f};
#pragma unroll
    for (int ks = 0; ks < 2; ++ks) {
      bf16x8 bk[4];
#pragma unroll
      for (int nf = 0; nf < 4; ++nf)
        bk[nf] = *reinterpret_cast<const bf16x8*>(
            kb + (size_t)(c0 + nf * 16 + lr) * 64 + ks * 32 + lg * 8);
#pragma unroll
      for (int mf = 0; mf < 2; ++mf)
#pragma unroll
        for (int nf = 0; nf < 4; ++nf)
          s[mf][nf] = __builtin_amdgcn_mfma_f32_16x16x32_bf16(a_q[mf][ks], bk[nf], s[mf][nf], 0, 0, 0);
    }
    int msk[4];
#pragma unroll
    for (int nf = 0; nf < 4; ++nf) msk[nf] = pmb[c0 + nf * 16 + lr];
#pragma unroll
    for (int mf = 0; mf < 2; ++mf)
#pragma unroll
      for (int nf = 0; nf < 4; ++nf)
#pragma unroll
        for (int r = 0; r < 4; ++r) {
          float e = msk[nf] ? 0.f : __expf(s[mf][nf][r] * 0.125f);
          l_run[mf][r] += e;
          E_lds[mf * 16 + lg * 4 + r][c0 + nf * 16 + lr] = f2bf(e);
        }
  }

  // row-sum reduce over 16 lr lanes, then cross-wave combine
#pragma unroll
  for (int mf = 0; mf < 2; ++mf)
#pragma unroll
    for (int r = 0; r < 4; ++r) {
      float v = l_run[mf][r];
      v += __shfl_xor(v, 1); v += __shfl_xor(v, 2);
      v += __shfl_xor(v, 4); v += __shfl_xor(v, 8);
      if (lr == 0) lw[w][mf * 16 + lg * 4 + r] = v;
    }
  __syncthreads();
  if (threadIdx.x < 32) {
    float s = 0.f;
#pragma unroll
    for (int ww = 0; ww < 8; ++ww) s += lw[ww][threadIdx.x];
    float li = 1.f / s;
    linv_s[threadIdx.x] = li;
    linv_ws[(size_t)bh * 1024 + q0 + threadIdx.x] = li;
  }
  __syncthreads();

  // write phase: 16 threads/row; lane cb covers cols cb*8 + i*128 -> per-instruction
  // 512B (f32) / 256B (bf16) contiguous segments.
  {
    const int row = threadIdx.x >> 4;
    const int cb = threadIdx.x & 15;
    const float sc = linv_s[row];
    float* rowp = attn_out + ((size_t)bh << 20) + (size_t)(q0 + row) * 1024;
    unsigned short* ebrow = eb + ((size_t)bh << 20) + (size_t)(q0 + row) * 1024;
#pragma unroll
    for (int i = 0; i < 8; ++i) {
      int c8 = cb * 8 + i * 128;
      bf16x8 ev = *reinterpret_cast<const bf16x8*>(&E_lds[row][c8]);
      f32x4 o0, o1;
#pragma unroll
      for (int j = 0; j < 4; ++j) o0[j] = bf2f((unsigned short)ev[j]) * sc;
#pragma unroll
      for (int j = 0; j < 4; ++j) o1[j] = bf2f((unsigned short)ev[4 + j]) * sc;
      *reinterpret_cast<f32x4*>(rowp + c8) = o0;
      *reinterpret_cast<f32x4*>(rowp + c8 + 4) = o1;
      *reinterpret_cast<bf16x8*>(ebrow + c8) = ev;
    }
  }
}

// ---------------- PV: O = E @ V * linv  (3-buffer counted-vmcnt pipeline) ----------------
// A = eb bf16 [bh][1024][1024], B = vt bf16 [512][8192]. BM=BN=128, BK=32, K=1024.
// 4096 flat blocks XCD-swizzled (nt innermost -> A-panel L2 reuse), 256 threads.
// STAGE = 4 vmem instr/thread; 3 tiles in flight -> steady-state vmcnt(8).
__launch_bounds__(256)
__global__ void pv_kernel(const unsigned short* __restrict__ eb,
                          const unsigned short* __restrict__ vt,
                          const float* __restrict__ linv_ws,
                          unsigned short* __restrict__ o_ws) {
  const int wg = (blockIdx.x & 7) * 512 + (blockIdx.x >> 3);
  const int nt = wg & 3, mt = (wg >> 2) & 7, bh = wg >> 5;
  const int b = bh >> 4, h = bh & 15;
  const int m0 = mt * 128, n0 = nt * 128;

  __shared__ unsigned short Asm[3][128 * 32];   // 24KB
  __shared__ unsigned short Bsm[3][128 * 32];   // 24KB
  const int w = threadIdx.x >> 6, l = threadIdx.x & 63;
  const int wr = w >> 1, wc = w & 1, lr = l & 15, lg = l >> 4;

  f32x4 acc[4][4];
#pragma unroll
  for (int mi = 0; mi < 4; ++mi)
#pragma unroll
    for (int ni = 0; ni < 4; ++ni) acc[mi][ni] = (f32x4){0.f, 0.f, 0.f, 0.f};

  const int srow = threadIdx.x >> 2;            // 0..63
  const int scol = (threadIdx.x & 3) * 8;       // 0,8,16,24
  const unsigned short* gA0 = eb + ((size_t)bh << 20) + (size_t)(m0 + srow) * 1024 + scol;
  const unsigned short* gA1 = gA0 + (size_t)64 * 1024;
  const unsigned short* gB0 = vt + (size_t)(n0 + srow) * 8192 + (size_t)b * 1024 + scol;
  const unsigned short* gB1 = gB0 + (size_t)64 * 8192;
  const int ldsoff = w * 512;

  auto STAGE = [&](int buf, int kt) {
    int k0 = kt * 32;
    gload_lds16(gA0 + k0, &Asm[buf][ldsoff]);
    gload_lds16(gA1 + k0, &Asm[buf][64 * 32 + ldsoff]);
    gload_lds16(gB0 + k0, &Bsm[buf][ldsoff]);
    gload_lds16(gB1 + k0, &Bsm[buf][64 * 32 + ldsoff]);
  };
  auto COMPUTE = [&](int buf) {
    bf16x8 a[4], bb[4];
#pragma unroll
    for (int mi = 0; mi < 4; ++mi)
      a[mi] = *reinterpret_cast<const bf16x8*>(&Asm[buf][(wr * 64 + mi * 16 + lr) * 32 + lg * 8]);
#pragma unroll
    for (int ni = 0; ni < 4; ++ni)
      bb[ni] = *reinterpret_cast<const bf16x8*>(&Bsm[buf][(wc * 64 + ni * 16 + lr) * 32 + lg * 8]);
    __builtin_amdgcn_s_setprio(1);
#pragma unroll
    for (int mi = 0; mi < 4; ++mi)
#pragma unroll
      for (int ni = 0; ni < 4; ++ni)
        acc[mi][ni] = __builtin_amdgcn_mfma_f32_16x16x32_bf16(a[mi], bb[ni], acc[mi][ni], 0, 0, 0);
    __builtin_amdgcn_s_setprio(0);
  };

  // prologue: 3 tiles in flight (12 vmem instr)
  STAGE(0, 0); STAGE(1, 1); STAGE(2, 2);
  int cur = 0;
  for (int kt = 0; kt < 29; ++kt) {
    WAITV(8);                 // tile kt's 4 loads retired (in-order vmcnt)
    BAR();                    // all waves' slices of buffer cur complete
    COMPUTE(cur);
    BAR();                    // no wave still reads buffer cur
    STAGE(cur, kt + 3);
    cur = (cur == 2) ? 0 : cur + 1;
  }
  // tail: tiles 29,30,31 (no more staging; counts decrease)
  WAITV(8); BAR(); COMPUTE(cur); cur = (cur == 2) ? 0 : cur + 1;
  WAITV(4); BAR(); COMPUTE(cur); cur = (cur == 2) ? 0 : cur + 1;
  WAITV(0); BAR(); COMPUTE(cur);

  // per-row 1/l (loaded after the loop so vmcnt math above stays exact)
  float linv_r[4][4];
  {
    const float* lrow = linv_ws + (size_t)bh * 1024 + m0 + wr * 64 + lg * 4;
#pragma unroll
    for (int mi = 0; mi < 4; ++mi)
#pragma unroll
      for (int r = 0; r < 4; ++r) linv_r[mi][r] = lrow[mi * 16 + r];
  }

  // epilogue: O tile * linv -> o_ws bf16 [b][s][h*512+c]
#pragma unroll
  for (int mi = 0; mi < 4; ++mi)
#pragma unroll
    for (int ni = 0; ni < 4; ++ni)
#pragma unroll
      for (int r = 0; r < 4; ++r) {
        int row = m0 + wr * 64 + mi * 16 + lg * 4 + r;
        int col = n0 + wc * 64 + ni * 16 + lr;
        o_ws[(size_t)(b * 1024 + row) * 8192 + h * 512 + col] =
            f2bf(acc[mi][ni][r] * linv_r[mi][r]);
      }
}

// ---------------- GEMM2: y = o @ W2 + b2  (3-buffer counted-vmcnt pipeline) ----------------
// BM=64, BN=128, BK=32, 512 blocks, flat grid XCD-swizzled, nt INNER.
// STAGE = 3 vmem instr/thread; 3 tiles in flight -> steady-state vmcnt(6).
__launch_bounds__(256)
__global__ void gemm2_kernel(const unsigned short* __restrict__ o_ws,
                             const unsigned short* __restrict__ w2t,
                             const float* __restrict__ b2,
                             float* __restrict__ y) {
  const int wg = (blockIdx.x & 7) * 64 + (blockIdx.x >> 3);
  const int nt = wg & 3, mt = wg >> 2;
  const int m0 = mt * 64, n0 = nt * 128;

  __shared__ unsigned short As[3][64 * 32];     // 12KB
  __shared__ unsigned short Bs[3][128 * 32];    // 24KB
  const int w = threadIdx.x >> 6, l = threadIdx.x & 63;
  const int wr = w >> 1, wc = w & 1, lr = l & 15, lg = l >> 4;

  f32x4 acc[2][4];
#pragma unroll
  for (int mi = 0; mi < 2; ++mi)
#pragma unroll
    for (int ni = 0; ni < 4; ++ni) acc[mi][ni] = (f32x4){0.f, 0.f, 0.f, 0.f};

  const int srow = threadIdx.x >> 2;        // 0..63
  const int scol = (threadIdx.x & 3) * 8;   // 0,8,16,24
  const unsigned short* gA  = o_ws + (size_t)(m0 + srow) * 8192 + scol;
  const unsigned short* gB0 = w2t + (size_t)(n0 + srow) * 8192 + scol;
  const unsigned short* gB1 = gB0 + (size_t)64 * 8192;
  const int ldsoff = w * 512;

  auto STAGE = [&](int buf, int kt) {
    int k0 = kt * 32;
    gload_lds16(gA + k0, &As[buf][ldsoff]);
    gload_lds16(gB0 + k0, &Bs[buf][ldsoff]);
    gload_lds16(gB1 + k0, &Bs[buf][64 * 32 + ldsoff]);
  };

  auto COMPUTE = [&](int buf) {
    bf16x8 a[2], bb[4];
#pragma unroll
    for (int mi = 0; mi < 2; ++mi)
      a[mi] = *reinterpret_cast<const bf16x8*>(&As[buf][(wr * 32 + mi * 16 + lr) * 32 + lg * 8]);
#pragma unroll
    for (int ni = 0; ni < 4; ++ni)
      bb[ni] = *reinterpret_cast<const bf16x8*>(&Bs[buf][(wc * 64 + ni * 16 + lr) * 32 + lg * 8]);
    __builtin_amdgcn_s_setprio(1);
#pragma unroll
    for (int mi = 0; mi < 2; ++mi)
#pragma unroll
      for (int ni = 0; ni < 4; ++ni)
        acc[mi][ni] = __builtin_amdgcn_mfma_f32_16x16x32_bf16(a[mi], bb[ni], acc[mi][ni], 0, 0, 0);
    __builtin_amdgcn_s_setprio(0);
  };

  STAGE(0, 0); STAGE(1, 1); STAGE(2, 2);
  int cur = 0;
  for (int kt = 0; kt < 253; ++kt) {
    WAITV(6);
    BAR();
    COMPUTE(cur);
    BAR();
    STAGE(cur, kt + 3);
    cur = (cur == 2) ? 0 : cur + 1;
  }
  WAITV(6); BAR(); COMPUTE(cur); cur = (cur == 2) ? 0 : cur + 1;
  WAITV(3); BAR(); COMPUTE(cur); cur = (cur == 2) ? 0 : cur + 1;
  WAITV(0); BAR(); COMPUTE(cur);

#pragma unroll
  for (int mi = 0; mi < 2; ++mi)
#pragma unroll
    for (int ni = 0; ni < 4; ++ni) {
      int col = n0 + wc * 64 + ni * 16 + lr;
      float bias = b2[col];
#pragma unroll
      for (int r = 0; r < 4; ++r)
        y[(size_t)(m0 + wr * 32 + mi * 16 + lg * 4 + r) * 512 + col] = acc[mi][ni][r] + bias;
    }
}

// ---------------- launch ----------------
extern "C" void kernel_launch(void* const* d_in, const int* in_sizes, int n_in,
                              void* d_out, int out_size, void* d_ws, size_t ws_size,
                              hipStream_t stream) {
  const float* v   = (const float*)d_in[0];
  const int*   pad = (const int*)d_in[1];
  const float* W1  = (const float*)d_in[2];
  const float* b1  = (const float*)d_in[3];
  const float* W2  = (const float*)d_in[4];
  const float* b2  = (const float*)d_in[5];
  float* out  = (float*)d_out;
  float* attn = out + (size_t)8 * 1024 * 512;

  char* ws = (char*)d_ws;
  unsigned short* w1t  = (unsigned short*)(ws);               //   2 MB  [2048][512]
  unsigned short* w2t  = (unsigned short*)(ws + 2097152);     //   8 MB  [512][8192]
  unsigned short* vt   = (unsigned short*)(ws + 10485760);    //   8 MB  [512][8192]
  unsigned short* vbf  = (unsigned short*)(ws + 18874368);    //   8 MB  [8192][512]
  unsigned short* q_ws = (unsigned short*)(ws + 27262976);    //  16 MB  [128][1024][64]
  unsigned short* k_ws = (unsigned short*)(ws + 44040192);    //  16 MB  [128][1024][64]
  unsigned short* o_ws = (unsigned short*)(ws + 60817408);    // 134 MB  [8192][8192]
  unsigned short* eb   = (unsigned short*)(ws + 195035136);   // 268 MB  [128][1024][1024]
  float*          linv = (float*)(ws + 463470592);            // 0.5 MB  [128][1024]

  transpose_cvt_kernel<<<dim3(64, 16), 256, 0, stream>>>(W1, w1t, 512, 2048);
  transpose_cvt_kernel<<<dim3(16, 256), 256, 0, stream>>>(W2, w2t, 8192, 512);
  prep_v_kernel<<<dim3(16, 256), 256, 0, stream>>>(v, vbf, vt);
  gemm1_kernel<<<dim3(16, 64), 256, 0, stream>>>(vbf, w1t, b1, q_ws, k_ws);
  scores_kernel<<<4096, 512, 0, stream>>>(q_ws, k_ws, pad, attn, eb, linv);
  pv_kernel<<<4096, 256, 0, stream>>>(eb, vt, linv, o_ws);
  gemm2_kernel<<<512, 256, 0, stream>>>(o_ws, w2t, b2, out);
}

// Round 17
// 673.151 us; speedup vs baseline: 1.1061x; 1.0031x over previous
//
#include <hip/hip_runtime.h>

// MultiHeadAttention: v(8,1024,512) fp32, pad(8,1,1,1024) int, W1(512,2048), b1(2048),
// W2(8192,512), b2(512) -> out (8,1024,512) fp32 ++ attn (8,16,1024,1024) fp32.
// All matmuls in bf16 MFMA 16x16x32, fp32 accumulate.
// R17: R16 + LDS slot-swizzle (T2) in pv/gemm2: store slot s of row r from global
//      slot s^(r&3) (pre-swizzled SOURCE, linear LDS dest), read slot lg^(row&3).
//      8-way -> 4-way bank conflict on every ds_read_b128.

typedef __attribute__((ext_vector_type(8))) short bf16x8;
typedef __attribute__((ext_vector_type(4))) float f32x4;
typedef __attribute__((ext_vector_type(4))) unsigned short u16x4;

__device__ __forceinline__ unsigned short f2bf(float f) {
  unsigned u = __builtin_bit_cast(unsigned, f);
  u += 0x7FFFu + ((u >> 16) & 1u);   // RTN-even
  return (unsigned short)(u >> 16);
}
__device__ __forceinline__ float bf2f(unsigned short u) {
  return __builtin_bit_cast(float, (unsigned)u << 16);
}

__device__ __forceinline__ void gload_lds16(const unsigned short* g, unsigned short* l) {
  __builtin_amdgcn_global_load_lds(
      (const __attribute__((address_space(1))) unsigned int*)(g),
      (__attribute__((address_space(3))) unsigned int*)(l), 16, 0, 0);
}

#define WAITV(N) do { asm volatile("s_waitcnt vmcnt(" #N ")" ::: "memory"); \
                      __builtin_amdgcn_sched_barrier(0); } while (0)
#define BAR()    do { __builtin_amdgcn_s_barrier(); \
                      __builtin_amdgcn_sched_barrier(0); } while (0)

// ---------------- preprocessing ----------------

// W transpose: in fp32 [R][C] -> out bf16 [C][R]
__global__ void transpose_cvt_kernel(const float* __restrict__ in,
                                     unsigned short* __restrict__ out,
                                     int R, int C) {
  __shared__ float tile[32][33];
  int c0 = blockIdx.x * 32, r0 = blockIdx.y * 32;
  int tx = threadIdx.x & 31, ty = threadIdx.x >> 5;
#pragma unroll
  for (int i = ty; i < 32; i += 8)
    tile[i][tx] = in[(size_t)(r0 + i) * C + (c0 + tx)];
  __syncthreads();
#pragma unroll
  for (int i = ty; i < 32; i += 8)
    out[(size_t)(c0 + i) * R + (r0 + tx)] = f2bf(tile[tx][i]);
}

// v fused prep: read v [8192][512] fp32 once; emit vbf (same layout bf16) and
// vt [512][8192] bf16 (transposed). grid (16, 256), 256 threads.
__global__ void prep_v_kernel(const float* __restrict__ v,
                              unsigned short* __restrict__ vbf,
                              unsigned short* __restrict__ vt) {
  __shared__ float tile[32][33];
  int c0 = blockIdx.x * 32, r0 = blockIdx.y * 32;
  int tx = threadIdx.x & 31, ty = threadIdx.x >> 5;
#pragma unroll
  for (int i = ty; i < 32; i += 8) {
    float val = v[(size_t)(r0 + i) * 512 + (c0 + tx)];
    tile[i][tx] = val;
    vbf[(size_t)(r0 + i) * 512 + (c0 + tx)] = f2bf(val);
  }
  __syncthreads();
#pragma unroll
  for (int i = ty; i < 32; i += 8)
    vt[(size_t)(c0 + i) * 8192 + (r0 + tx)] = f2bf(tile[tx][i]);
}

// ---------------- GEMM1: kq = v @ W1 + b1 ----------------
__launch_bounds__(256)
__global__ void gemm1_kernel(const unsigned short* __restrict__ vbf,
                             const unsigned short* __restrict__ w1t,
                             const float* __restrict__ b1,
                             unsigned short* __restrict__ q_ws,
                             unsigned short* __restrict__ k_ws) {
  const int m0 = blockIdx.y * 128, n0 = blockIdx.x * 128;
  const int w = threadIdx.x >> 6, l = threadIdx.x & 63;
  const int wr = w >> 1, wc = w & 1, lr = l & 15, lg = l >> 4;
  f32x4 acc[4][4];
#pragma unroll
  for (int mi = 0; mi < 4; ++mi)
#pragma unroll
    for (int ni = 0; ni < 4; ++ni) acc[mi][ni] = (f32x4){0.f, 0.f, 0.f, 0.f};

  for (int k0 = 0; k0 < 512; k0 += 32) {
    bf16x8 a[4], bb[4];
#pragma unroll
    for (int mi = 0; mi < 4; ++mi)
      a[mi] = *reinterpret_cast<const bf16x8*>(
          vbf + (size_t)(m0 + wr * 64 + mi * 16 + lr) * 512 + k0 + lg * 8);
#pragma unroll
    for (int ni = 0; ni < 4; ++ni)
      bb[ni] = *reinterpret_cast<const bf16x8*>(
          w1t + (size_t)(n0 + wc * 64 + ni * 16 + lr) * 512 + k0 + lg * 8);
#pragma unroll
    for (int mi = 0; mi < 4; ++mi)
#pragma unroll
      for (int ni = 0; ni < 4; ++ni)
        acc[mi][ni] = __builtin_amdgcn_mfma_f32_16x16x32_bf16(a[mi], bb[ni], acc[mi][ni], 0, 0, 0);
  }
#pragma unroll
  for (int mi = 0; mi < 4; ++mi)
#pragma unroll
    for (int ni = 0; ni < 4; ++ni) {
      int col = n0 + wc * 64 + ni * 16 + lr;
      int h = col >> 7, j = col & 127;
      float bias = b1[col];
#pragma unroll
      for (int r = 0; r < 4; ++r) {
        int row = m0 + wr * 64 + mi * 16 + lg * 4 + r;
        int bb_ = row >> 10, s = row & 1023;
        unsigned short bv = f2bf(acc[mi][ni][r] + bias);
        size_t base = ((size_t)(bb_ * 16 + h) << 16) + (size_t)s * 64;
        if (j < 64) k_ws[base + j] = bv;
        else        q_ws[base + j - 64] = bv;
      }
    }
}

// ---------------- scores: QK^T -> exp (no max-sub) -> attn fp32 + E bf16 + 1/l ----------------
// QBLK=32, 4096 blocks (XCD-swizzled), 512 threads (8 waves); wave w owns cols w*128..+127.
__launch_bounds__(512)
__global__ void scores_kernel(const unsigned short* __restrict__ q_ws,
                              const unsigned short* __restrict__ k_ws,
                              const int* __restrict__ pad,           // [8][1024]
                              float* __restrict__ attn_out,          // [8][16][1024][1024]
                              unsigned short* __restrict__ eb,       // bf16 [128][1024][1024]
                              float* __restrict__ linv_ws) {         // [128][1024]
  const int wg = (blockIdx.x & 7) * 512 + (blockIdx.x >> 3);
  const int qt = wg & 31, h = (wg >> 5) & 15, b = wg >> 9;
  const int bh = b * 16 + h, q0 = qt * 32;
  const int w = threadIdx.x >> 6, l = threadIdx.x & 63;
  const int lr = l & 15, lg = l >> 4;

  __shared__ unsigned short E_lds[32][1032];  // 66KB
  __shared__ float lw[8][32];
  __shared__ float linv_s[32];

  const unsigned short* qb = q_ws + ((size_t)bh << 16);
  const unsigned short* kb = k_ws + ((size_t)bh << 16);
  const int* pmb = pad + b * 1024;

  bf16x8 a_q[2][2];
#pragma unroll
  for (int mf = 0; mf < 2; ++mf)
#pragma unroll
    for (int ks = 0; ks < 2; ++ks)
      a_q[mf][ks] = *reinterpret_cast<const bf16x8*>(
          qb + (size_t)(q0 + mf * 16 + lr) * 64 + ks * 32 + lg * 8);

  float l_run[2][4];
#pragma unroll
  for (int mf = 0; mf < 2; ++mf)
#pragma unroll
    for (int r = 0; r < 4; ++r) l_run[mf][r] = 0.f;

#pragma unroll
  for (int sub = 0; sub < 2; ++sub) {
    const int c0 = w * 128 + sub * 64;
    f32x4 s[2][4];
#pragma unroll
    for (int mf = 0; mf < 2; ++mf)
#pragma unroll
      for (int nf = 0; nf < 4; ++nf) s[mf][nf] = (f32x4){0.f, 0.f, 0.f, 0.f};
#pragma unroll
    for (int ks = 0; ks < 2; ++ks) {
      bf16x8 bk[4];
#pragma unroll
      for (int nf = 0; nf < 4; ++nf)
        bk[nf] = *reinterpret_cast<const bf16x8*>(
            kb + (size_t)(c0 + nf * 16 + lr) * 64 + ks * 32 + lg * 8);
#pragma unroll
      for (int mf = 0; mf < 2; ++mf)
#pragma unroll
        for (int nf = 0; nf < 4; ++nf)
          s[mf][nf] = __builtin_amdgcn_mfma_f32_16x16x32_bf16(a_q[mf][ks], bk[nf], s[mf][nf], 0, 0, 0);
    }
    int msk[4];
#pragma unroll
    for (int nf = 0; nf < 4; ++nf) msk[nf] = pmb[c0 + nf * 16 + lr];
#pragma unroll
    for (int mf = 0; mf < 2; ++mf)
#pragma unroll
      for (int nf = 0; nf < 4; ++nf)
#pragma unroll
        for (int r = 0; r < 4; ++r) {
          float e = msk[nf] ? 0.f : __expf(s[mf][nf][r] * 0.125f);
          l_run[mf][r] += e;
          E_lds[mf * 16 + lg * 4 + r][c0 + nf * 16 + lr] = f2bf(e);
        }
  }

  // row-sum reduce over 16 lr lanes, then cross-wave combine
#pragma unroll
  for (int mf = 0; mf < 2; ++mf)
#pragma unroll
    for (int r = 0; r < 4; ++r) {
      float v = l_run[mf][r];
      v += __shfl_xor(v, 1); v += __shfl_xor(v, 2);
      v += __shfl_xor(v, 4); v += __shfl_xor(v, 8);
      if (lr == 0) lw[w][mf * 16 + lg * 4 + r] = v;
    }
  __syncthreads();
  if (threadIdx.x < 32) {
    float s = 0.f;
#pragma unroll
    for (int ww = 0; ww < 8; ++ww) s += lw[ww][threadIdx.x];
    float li = 1.f / s;
    linv_s[threadIdx.x] = li;
    linv_ws[(size_t)bh * 1024 + q0 + threadIdx.x] = li;
  }
  __syncthreads();

  // write phase: 16 threads/row; lane cb covers cols cb*8 + i*128 -> per-instruction
  // 512B (f32) / 256B (bf16) contiguous segments.
  {
    const int row = threadIdx.x >> 4;
    const int cb = threadIdx.x & 15;
    const float sc = linv_s[row];
    float* rowp = attn_out + ((size_t)bh << 20) + (size_t)(q0 + row) * 1024;
    unsigned short* ebrow = eb + ((size_t)bh << 20) + (size_t)(q0 + row) * 1024;
#pragma unroll
    for (int i = 0; i < 8; ++i) {
      int c8 = cb * 8 + i * 128;
      bf16x8 ev = *reinterpret_cast<const bf16x8*>(&E_lds[row][c8]);
      f32x4 o0, o1;
#pragma unroll
      for (int j = 0; j < 4; ++j) o0[j] = bf2f((unsigned short)ev[j]) * sc;
#pragma unroll
      for (int j = 0; j < 4; ++j) o1[j] = bf2f((unsigned short)ev[4 + j]) * sc;
      *reinterpret_cast<f32x4*>(rowp + c8) = o0;
      *reinterpret_cast<f32x4*>(rowp + c8 + 4) = o1;
      *reinterpret_cast<bf16x8*>(ebrow + c8) = ev;
    }
  }
}

// ---------------- PV: O = E @ V * linv  (3-buffer counted-vmcnt + slot swizzle) ----------------
// A = eb bf16 [bh][1024][1024], B = vt bf16 [512][8192]. BM=BN=128, BK=32, K=1024.
// 4096 flat blocks XCD-swizzled (nt innermost), 256 threads. steady-state vmcnt(8).
// LDS slot swizzle: LDS[row][slot] holds global slot^(row&3); read slot lg^(lr&3).
__launch_bounds__(256)
__global__ void pv_kernel(const unsigned short* __restrict__ eb,
                          const unsigned short* __restrict__ vt,
                          const float* __restrict__ linv_ws,
                          unsigned short* __restrict__ o_ws) {
  const int wg = (blockIdx.x & 7) * 512 + (blockIdx.x >> 3);
  const int nt = wg & 3, mt = (wg >> 2) & 7, bh = wg >> 5;
  const int b = bh >> 4, h = bh & 15;
  const int m0 = mt * 128, n0 = nt * 128;

  __shared__ unsigned short Asm[3][128 * 32];   // 24KB
  __shared__ unsigned short Bsm[3][128 * 32];   // 24KB
  const int w = threadIdx.x >> 6, l = threadIdx.x & 63;
  const int wr = w >> 1, wc = w & 1, lr = l & 15, lg = l >> 4;

  f32x4 acc[4][4];
#pragma unroll
  for (int mi = 0; mi < 4; ++mi)
#pragma unroll
    for (int ni = 0; ni < 4; ++ni) acc[mi][ni] = (f32x4){0.f, 0.f, 0.f, 0.f};

  const int srow = threadIdx.x >> 2;                         // 0..63
  const int scol = (((threadIdx.x & 3) ^ (srow & 3)) * 8);   // pre-swizzled SOURCE slot
  const unsigned short* gA0 = eb + ((size_t)bh << 20) + (size_t)(m0 + srow) * 1024 + scol;
  const unsigned short* gA1 = gA0 + (size_t)64 * 1024;       // row+64: (row&3) unchanged
  const unsigned short* gB0 = vt + (size_t)(n0 + srow) * 8192 + (size_t)b * 1024 + scol;
  const unsigned short* gB1 = gB0 + (size_t)64 * 8192;
  const int ldsoff = w * 512;
  const int sl = (lg ^ (lr & 3)) * 8;                        // swizzled READ slot

  auto STAGE = [&](int buf, int kt) {
    int k0 = kt * 32;
    gload_lds16(gA0 + k0, &Asm[buf][ldsoff]);
    gload_lds16(gA1 + k0, &Asm[buf][64 * 32 + ldsoff]);
    gload_lds16(gB0 + k0, &Bsm[buf][ldsoff]);
    gload_lds16(gB1 + k0, &Bsm[buf][64 * 32 + ldsoff]);
  };
  auto COMPUTE = [&](int buf) {
    bf16x8 a[4], bb[4];
#pragma unroll
    for (int mi = 0; mi < 4; ++mi)
      a[mi] = *reinterpret_cast<const bf16x8*>(&Asm[buf][(wr * 64 + mi * 16 + lr) * 32 + sl]);
#pragma unroll
    for (int ni = 0; ni < 4; ++ni)
      bb[ni] = *reinterpret_cast<const bf16x8*>(&Bsm[buf][(wc * 64 + ni * 16 + lr) * 32 + sl]);
    __builtin_amdgcn_s_setprio(1);
#pragma unroll
    for (int mi = 0; mi < 4; ++mi)
#pragma unroll
      for (int ni = 0; ni < 4; ++ni)
        acc[mi][ni] = __builtin_amdgcn_mfma_f32_16x16x32_bf16(a[mi], bb[ni], acc[mi][ni], 0, 0, 0);
    __builtin_amdgcn_s_setprio(0);
  };

  // prologue: 3 tiles in flight (12 vmem instr)
  STAGE(0, 0); STAGE(1, 1); STAGE(2, 2);
  int cur = 0;
  for (int kt = 0; kt < 29; ++kt) {
    WAITV(8);                 // tile kt's 4 loads retired (in-order vmcnt)
    BAR();                    // all waves' slices of buffer cur complete
    COMPUTE(cur);
    BAR();                    // no wave still reads buffer cur
    STAGE(cur, kt + 3);
    cur = (cur == 2) ? 0 : cur + 1;
  }
  // tail: tiles 29,30,31
  WAITV(8); BAR(); COMPUTE(cur); cur = (cur == 2) ? 0 : cur + 1;
  WAITV(4); BAR(); COMPUTE(cur); cur = (cur == 2) ? 0 : cur + 1;
  WAITV(0); BAR(); COMPUTE(cur);

  // per-row 1/l (after the loop so vmcnt math stays exact)
  float linv_r[4][4];
  {
    const float* lrow = linv_ws + (size_t)bh * 1024 + m0 + wr * 64 + lg * 4;
#pragma unroll
    for (int mi = 0; mi < 4; ++mi)
#pragma unroll
      for (int r = 0; r < 4; ++r) linv_r[mi][r] = lrow[mi * 16 + r];
  }

  // epilogue: O tile * linv -> o_ws bf16 [b][s][h*512+c]
#pragma unroll
  for (int mi = 0; mi < 4; ++mi)
#pragma unroll
    for (int ni = 0; ni < 4; ++ni)
#pragma unroll
      for (int r = 0; r < 4; ++r) {
        int row = m0 + wr * 64 + mi * 16 + lg * 4 + r;
        int col = n0 + wc * 64 + ni * 16 + lr;
        o_ws[(size_t)(b * 1024 + row) * 8192 + h * 512 + col] =
            f2bf(acc[mi][ni][r] * linv_r[mi][r]);
      }
}

// ---------------- GEMM2: y = o @ W2 + b2  (3-buffer counted-vmcnt + slot swizzle) ----------------
// BM=64, BN=128, BK=32, 512 blocks, flat grid XCD-swizzled, nt INNER. vmcnt(6).
__launch_bounds__(256)
__global__ void gemm2_kernel(const unsigned short* __restrict__ o_ws,
                             const unsigned short* __restrict__ w2t,
                             const float* __restrict__ b2,
                             float* __restrict__ y) {
  const int wg = (blockIdx.x & 7) * 64 + (blockIdx.x >> 3);
  const int nt = wg & 3, mt = wg >> 2;
  const int m0 = mt * 64, n0 = nt * 128;

  __shared__ unsigned short As[3][64 * 32];     // 12KB
  __shared__ unsigned short Bs[3][128 * 32];    // 24KB
  const int w = threadIdx.x >> 6, l = threadIdx.x & 63;
  const int wr = w >> 1, wc = w & 1, lr = l & 15, lg = l >> 4;

  f32x4 acc[2][4];
#pragma unroll
  for (int mi = 0; mi < 2; ++mi)
#pragma unroll
    for (int ni = 0; ni < 4; ++ni) acc[mi][ni] = (f32x4){0.f, 0.f, 0.f, 0.f};

  const int srow = threadIdx.x >> 2;                         // 0..63
  const int scol = (((threadIdx.x & 3) ^ (srow & 3)) * 8);   // pre-swizzled SOURCE slot
  const unsigned short* gA  = o_ws + (size_t)(m0 + srow) * 8192 + scol;
  const unsigned short* gB0 = w2t + (size_t)(n0 + srow) * 8192 + scol;
  const unsigned short* gB1 = gB0 + (size_t)64 * 8192;
  const int ldsoff = w * 512;
  const int sl = (lg ^ (lr & 3)) * 8;                        // swizzled READ slot

  auto STAGE = [&](int buf, int kt) {
    int k0 = kt * 32;
    gload_lds16(gA + k0, &As[buf][ldsoff]);
    gload_lds16(gB0 + k0, &Bs[buf][ldsoff]);
    gload_lds16(gB1 + k0, &Bs[buf][64 * 32 + ldsoff]);
  };

  auto COMPUTE = [&](int buf) {
    bf16x8 a[2], bb[4];
#pragma unroll
    for (int mi = 0; mi < 2; ++mi)
      a[mi] = *reinterpret_cast<const bf16x8*>(&As[buf][(wr * 32 + mi * 16 + lr) * 32 + sl]);
#pragma unroll
    for (int ni = 0; ni < 4; ++ni)
      bb[ni] = *reinterpret_cast<const bf16x8*>(&Bs[buf][(wc * 64 + ni * 16 + lr) * 32 + sl]);
    __builtin_amdgcn_s_setprio(1);
#pragma unroll
    for (int mi = 0; mi < 2; ++mi)
#pragma unroll
      for (int ni = 0; ni < 4; ++ni)
        acc[mi][ni] = __builtin_amdgcn_mfma_f32_16x16x32_bf16(a[mi], bb[ni], acc[mi][ni], 0, 0, 0);
    __builtin_amdgcn_s_setprio(0);
  };

  STAGE(0, 0); STAGE(1, 1); STAGE(2, 2);
  int cur = 0;
  for (int kt = 0; kt < 253; ++kt) {
    WAITV(6);
    BAR();
    COMPUTE(cur);
    BAR();
    STAGE(cur, kt + 3);
    cur = (cur == 2) ? 0 : cur + 1;
  }
  WAITV(6); BAR(); COMPUTE(cur); cur = (cur == 2) ? 0 : cur + 1;
  WAITV(3); BAR(); COMPUTE(cur); cur = (cur == 2) ? 0 : cur + 1;
  WAITV(0); BAR(); COMPUTE(cur);

#pragma unroll
  for (int mi = 0; mi < 2; ++mi)
#pragma unroll
    for (int ni = 0; ni < 4; ++ni) {
      int col = n0 + wc * 64 + ni * 16 + lr;
      float bias = b2[col];
#pragma unroll
      for (int r = 0; r < 4; ++r)
        y[(size_t)(m0 + wr * 32 + mi * 16 + lg * 4 + r) * 512 + col] = acc[mi][ni][r] + bias;
    }
}

// ---------------- launch ----------------
extern "C" void kernel_launch(void* const* d_in, const int* in_sizes, int n_in,
                              void* d_out, int out_size, void* d_ws, size_t ws_size,
                              hipStream_t stream) {
  const float* v   = (const float*)d_in[0];
  const int*   pad = (const int*)d_in[1];
  const float* W1  = (const float*)d_in[2];
  const float* b1  = (const float*)d_in[3];
  const float* W2  = (const float*)d_in[4];
  const float* b2  = (const float*)d_in[5];
  float* out  = (float*)d_out;
  float* attn = out + (size_t)8 * 1024 * 512;

  char* ws = (char*)d_ws;
  unsigned short* w1t  = (unsigned short*)(ws);               //   2 MB  [2048][512]
  unsigned short* w2t  = (unsigned short*)(ws + 2097152);     //   8 MB  [512][8192]
  unsigned short* vt   = (unsigned short*)(ws + 10485760);    //   8 MB  [512][8192]
  unsigned short* vbf  = (unsigned short*)(ws + 18874368);    //   8 MB  [8192][512]
  unsigned short* q_ws = (unsigned short*)(ws + 27262976);    //  16 MB  [128][1024][64]
  unsigned short* k_ws = (unsigned short*)(ws + 44040192);    //  16 MB  [128][1024][64]
  unsigned short* o_ws = (unsigned short*)(ws + 60817408);    // 134 MB  [8192][8192]
  unsigned short* eb   = (unsigned short*)(ws + 195035136);   // 268 MB  [128][1024][1024]
  float*          linv = (float*)(ws + 463470592);            // 0.5 MB  [128][1024]

  transpose_cvt_kernel<<<dim3(64, 16), 256, 0, stream>>>(W1, w1t, 512, 2048);
  transpose_cvt_kernel<<<dim3(16, 256), 256, 0, stream>>>(W2, w2t, 8192, 512);
  prep_v_kernel<<<dim3(16, 256), 256, 0, stream>>>(v, vbf, vt);
  gemm1_kernel<<<dim3(16, 64), 256, 0, stream>>>(vbf, w1t, b1, q_ws, k_ws);
  scores_kernel<<<4096, 512, 0, stream>>>(q_ws, k_ws, pad, attn, eb, linv);
  pv_kernel<<<4096, 256, 0, stream>>>(eb, vt, linv, o_ws);
  gemm2_kernel<<<512, 256, 0, stream>>>(o_ws, w2t, b2, out);
}